// Round 1
// baseline (890.561 us; speedup 1.0000x reference)
//
#include <hip/hip_runtime.h>
#include <hip/hip_fp16.h>
#include <math.h>

typedef unsigned short u16;
typedef float f32x4 __attribute__((ext_vector_type(4)));
typedef __bf16 bf16x8 __attribute__((ext_vector_type(8)));

__device__ __forceinline__ float b2f(u16 u) {
    union { unsigned int i; float f; } v; v.i = ((unsigned int)u) << 16; return v.f;
}
__device__ __forceinline__ u16 f2b(float f) {
    union { float f; unsigned int i; } v; v.f = f;
    unsigned int lsb = (v.i >> 16) & 1u;
    return (u16)((v.i + 0x7fffu + lsb) >> 16);   // RNE
}

// async global->LDS, 16B per lane; lds dest = wave-uniform base + lane*16
__device__ __forceinline__ void gld16(const u16* g, u16* l) {
    __builtin_amdgcn_global_load_lds(
        (const __attribute__((address_space(1))) unsigned int*)g,
        (__attribute__((address_space(3))) unsigned int*)l,
        16, 0, 0);
}

// ---------------------------------------------------------------------------
// CSR build: counts -> block scan -> global scan -> fill
// ---------------------------------------------------------------------------
__global__ __launch_bounds__(256)
void k_count(const int* __restrict__ dst, int* __restrict__ cnt, int E)
{
    int e = blockIdx.x * 256 + threadIdx.x;
    if (e < E) atomicAdd(&cnt[dst[e]], 1);
}

__global__ __launch_bounds__(256)
void k_scan1(const int* __restrict__ cnt, int* __restrict__ rowptr,
             int* __restrict__ bsum, int N)
{
    __shared__ int s[256];
    int t = threadIdx.x, i = blockIdx.x * 256 + t;
    int v = (i < N) ? cnt[i] : 0;
    s[t] = v;
    __syncthreads();
#pragma unroll
    for (int off = 1; off < 256; off <<= 1) {
        int add = (t >= off) ? s[t - off] : 0;
        __syncthreads();
        s[t] += add;
        __syncthreads();
    }
    if (i < N) rowptr[i] = s[t] - v;
    if (t == 255) bsum[blockIdx.x] = s[255];
}

__global__ __launch_bounds__(256)
void k_scan2(const int* __restrict__ bsum, int* __restrict__ bscan, int nb)
{
    __shared__ int s[256];
    int t = threadIdx.x;
    int g[4], e[4];
    int base = t * 4;
#pragma unroll
    for (int j = 0; j < 4; ++j) g[j] = (base + j < nb) ? bsum[base + j] : 0;
    e[0] = 0; e[1] = g[0]; e[2] = g[0] + g[1]; e[3] = g[0] + g[1] + g[2];
    int tsum = e[3] + g[3];
    s[t] = tsum;
    __syncthreads();
#pragma unroll
    for (int off = 1; off < 256; off <<= 1) {
        int add = (t >= off) ? s[t - off] : 0;
        __syncthreads();
        s[t] += add;
        __syncthreads();
    }
    int texcl = s[t] - tsum;
#pragma unroll
    for (int j = 0; j < 4; ++j)
        if (base + j < nb) bscan[base + j] = texcl + e[j];
}

__global__ __launch_bounds__(256)
void k_scan3(int* __restrict__ rowptr, const int* __restrict__ bscan,
             int* __restrict__ cursor, int N)
{
    int i = blockIdx.x * 256 + threadIdx.x;
    if (i >= N) return;
    int r = rowptr[i] + bscan[i >> 8];
    rowptr[i] = r;
    cursor[i] = r;
}

__global__ __launch_bounds__(256)
void k_fill(const int* __restrict__ src, const int* __restrict__ dst,
            int* __restrict__ cursor, int* __restrict__ col, int E)
{
    int e = blockIdx.x * 256 + threadIdx.x;
    if (e >= E) return;
    int pos = atomicAdd(&cursor[dst[e]], 1);
    col[pos] = src[e];
}

// transpose + f32->bf16 convert: out[n*K+k] = bf16(in[k*N+n])   (weights, tiny)
__global__ void k_T(const float* __restrict__ in, u16* __restrict__ out, int K, int N)
{
    int t = blockIdx.x * 256 + threadIdx.x;
    if (t >= K * N) return;
    int n = t / K, k = t % K;
    out[t] = f2b(in[k * N + n]);
}

// ---------------------------------------------------------------------------
// Fully fused GIN layer: aggregation + Hout = relu(Aeff @ Wa + ba) @ Wb + bb.
// Block = 64 nodes x 256 out cols, 4 waves (each 64x64 via 4x4 frags 16x16x32).
//
// Aggregation: 4 threads/row gather relu?(h[node]) + sum relu?(h[col_j]) with
// f32 accumulation, one bf16 round, written straight into LDS in the blocked
// MFMA-A layout:  elem(row,k) -> AH[(k>>5)*2048 + (row>>4)*512
//                                 + ((k>>3)&3)*128 + (row&15)*8 + (k&7)]
// so fragment reads are a[r] = AH[(kb*256 + r*64 + lane)*8] (conflict-free).
// AH (32 KB) is reused as the hidden buffer for phase 2 (A dead after phase 1).
// B chunks staged per K-step via global_load_lds width=16.
// LDS total: AH 32 KB + Bs 16 KB = 48 KB -> 3 blocks/CU.
// ---------------------------------------------------------------------------
template<int K, bool RELU, bool F32SRC>
__global__ __launch_bounds__(256)
void k_gin(const void* __restrict__ hsrc,
           const int* __restrict__ cnt, const int* __restrict__ rowptr,
           const int* __restrict__ col,
           const u16* __restrict__ WaT, const float* __restrict__ ba,
           const u16* __restrict__ WbT, const float* __restrict__ bb,
           u16* __restrict__ Hout)
{
    __shared__ u16 AH[64 * 256];     // 32 KB: Aeff (phase 1) then hidden (phase 2)
    __shared__ u16 Bs2[256 * 32];    // 16 KB

    const int tid = threadIdx.x, lane = tid & 63, wave = tid >> 6;
    const int bm0 = blockIdx.x * 64;
    const int lc = lane & 15, lr = (lane >> 4) * 4;
    const int cw0 = wave * 64;
    const int l15 = lane & 15, lq = lane >> 4;   // DMA lane roles

    // prefetch phase-1 B chunk 0 (independent of aggregation -> hides latency)
#pragma unroll
    for (int c = 0; c < 4; ++c)
        gld16(WaT + (size_t)(cw0 + c * 16 + l15) * K + lq * 8,
              Bs2 + (wave * 4 + c) * 512);

    // ---- fused aggregation into AH ----
    {
        const int r    = tid >> 2;          // 0..63 block row
        const int seg  = tid & 3;           // k segment
        const int node = bm0 + r;
        const int nn = cnt[node], rp = rowptr[node];
        constexpr int KSEG = K / 4;         // 64 (K=256) or 32 (K=128)
        constexpr int NP   = KSEG / 32;     // 2 or 1 passes of 32 k
        u16* const wbase = AH + (r >> 4) * 512 + (r & 15) * 8;
#pragma unroll
        for (int p = 0; p < NP; ++p) {
            const int k0 = seg * KSEG + p * 32;
            float acc[32];
#pragma unroll
            for (int i = 0; i < 32; ++i) acc[i] = 0.f;
            for (int j = -1; j < nn; ++j) {          // j==-1 is own row
                const int sIdx = (j < 0) ? node : col[rp + j];
                if (F32SRC) {
                    const float4* q = (const float4*)((const float*)hsrc + (size_t)sIdx * K + k0);
#pragma unroll
                    for (int cc = 0; cc < 8; ++cc) {
                        float4 v = q[cc];
                        if (RELU) {
                            v.x = fmaxf(v.x, 0.f); v.y = fmaxf(v.y, 0.f);
                            v.z = fmaxf(v.z, 0.f); v.w = fmaxf(v.w, 0.f);
                        }
                        acc[cc * 4 + 0] += v.x; acc[cc * 4 + 1] += v.y;
                        acc[cc * 4 + 2] += v.z; acc[cc * 4 + 3] += v.w;
                    }
                } else {
                    const uint4* q = (const uint4*)((const u16*)hsrc + (size_t)sIdx * K + k0);
#pragma unroll
                    for (int cc = 0; cc < 4; ++cc) {
                        u16 vs[8] __attribute__((aligned(16)));
                        *(uint4*)vs = q[cc];
#pragma unroll
                        for (int i2 = 0; i2 < 8; ++i2) {
                            float x = b2f(vs[i2]);
                            acc[cc * 8 + i2] += RELU ? fmaxf(x, 0.f) : x;
                        }
                    }
                }
            }
            u16* wp = wbase + (k0 >> 5) * 2048;
#pragma unroll
            for (int kc = 0; kc < 4; ++kc) {
                u16 tmp[8] __attribute__((aligned(16)));
#pragma unroll
                for (int jj = 0; jj < 8; ++jj) tmp[jj] = f2b(acc[kc * 8 + jj]);
                *(uint4*)(wp + kc * 128) = *(const uint4*)tmp;
            }
        }
    }
    __syncthreads();    // AH ready + B chunk-0 DMA drained (vmcnt+lgkmcnt+barrier)

    // ---- phase 1: hidden = relu(Aeff @ Wa + ba) ----
    constexpr int NK1 = K / 32;
    f32x4 acc1[4][4];
#pragma unroll
    for (int r = 0; r < 4; ++r)
#pragma unroll
        for (int c = 0; c < 4; ++c) acc1[r][c] = (f32x4){0.f, 0.f, 0.f, 0.f};

    for (int kb = 0; kb < NK1; ++kb) {
        bf16x8 a[4], b[4];
#pragma unroll
        for (int r = 0; r < 4; ++r)
            a[r] = *(const bf16x8*)&AH[(kb * 256 + r * 64 + lane) * 8];
#pragma unroll
        for (int c = 0; c < 4; ++c)
            b[c] = *(const bf16x8*)&Bs2[((wave * 4 + c) * 64 + lane) * 8];
#pragma unroll
        for (int r = 0; r < 4; ++r)
#pragma unroll
            for (int c = 0; c < 4; ++c)
                acc1[r][c] = __builtin_amdgcn_mfma_f32_16x16x32_bf16(a[r], b[c], acc1[r][c], 0, 0, 0);
        __syncthreads();                          // all Bs/AH reads done
        if (kb + 1 < NK1) {
#pragma unroll
            for (int c = 0; c < 4; ++c)
                gld16(WaT + (size_t)(cw0 + c * 16 + l15) * K + (kb + 1) * 32 + lq * 8,
                      Bs2 + (wave * 4 + c) * 512);
            __syncthreads();                      // drain DMA
        }
    }

    // prefetch phase-2 B chunk 0 (hides under epilogue-1 LDS writes)
#pragma unroll
    for (int c = 0; c < 4; ++c)
        gld16(WbT + (size_t)(cw0 + c * 16 + l15) * 256 + lq * 8,
              Bs2 + (wave * 4 + c) * 512);

    // epilogue 1 -> AH (blocked A-layout for phase 2); safe: phase-1 reads drained
    // C/D layout: col = lane&15 (=lc), row = (lane>>4)*4 + i (=lr+i)
#pragma unroll
    for (int c = 0; c < 4; ++c) {
        const int n = cw0 + c * 16 + lc;           // hidden col = phase-2 k
        const float bv = ba[n];
        const int nb = (n >> 5) * 256 + ((n >> 3) & 3) * 16;
#pragma unroll
        for (int r = 0; r < 4; ++r)
#pragma unroll
            for (int i = 0; i < 4; ++i)
                AH[(nb + r * 64 + lr + i) * 8 + (n & 7)] = f2b(fmaxf(acc1[r][c][i] + bv, 0.f));
    }
    __syncthreads();                              // hidden ready + B DMA drained

    // ---- phase 2: out = hidden @ Wb + bb ----
    f32x4 acc2[4][4];
#pragma unroll
    for (int r = 0; r < 4; ++r)
#pragma unroll
        for (int c = 0; c < 4; ++c) acc2[r][c] = (f32x4){0.f, 0.f, 0.f, 0.f};

    for (int kb = 0; kb < 8; ++kb) {
        bf16x8 a[4], b[4];
#pragma unroll
        for (int r = 0; r < 4; ++r)
            a[r] = *(const bf16x8*)&AH[(kb * 256 + r * 64 + lane) * 8];
#pragma unroll
        for (int c = 0; c < 4; ++c)
            b[c] = *(const bf16x8*)&Bs2[((wave * 4 + c) * 64 + lane) * 8];
#pragma unroll
        for (int r = 0; r < 4; ++r)
#pragma unroll
            for (int c = 0; c < 4; ++c)
                acc2[r][c] = __builtin_amdgcn_mfma_f32_16x16x32_bf16(a[r], b[c], acc2[r][c], 0, 0, 0);
        __syncthreads();
        if (kb < 7) {
#pragma unroll
            for (int c = 0; c < 4; ++c)
                gld16(WbT + (size_t)(cw0 + c * 16 + l15) * 256 + (kb + 1) * 32 + lq * 8,
                      Bs2 + (wave * 4 + c) * 512);
            __syncthreads();
        }
    }
#pragma unroll
    for (int c = 0; c < 4; ++c) {
        const int n = cw0 + c * 16 + lc;
        const float bv = bb[n];
#pragma unroll
        for (int r = 0; r < 4; ++r)
#pragma unroll
            for (int i = 0; i < 4; ++i)
                Hout[(size_t)(bm0 + r * 16 + lr + i) * 256 + n] = f2b(acc2[r][c][i] + bv);
    }
}

// ---------------------------------------------------------------------------
// Classifier linear: C[f32] = leaky(A[bf16] @ WT^T), N=512 via 2 n-blocks.
// ---------------------------------------------------------------------------
__global__ __launch_bounds__(256)
void k_lin(const u16* __restrict__ A, const u16* __restrict__ WT,
           float* __restrict__ C)
{
    __shared__ u16 As[64 * 40];
    __shared__ u16 Bs[256 * 40];
    const int tid = threadIdx.x, lane = tid & 63, wave = tid >> 6;
    const int bm0 = blockIdx.x * 64, bn0 = blockIdx.y * 256;
    const int fm = lane & 15, fk = (lane >> 4) * 8;
    const int lc = lane & 15, lr = (lane >> 4) * 4;
    const int cw0 = wave * 64;
    const int sr = tid >> 2, sc = tid & 3;

    f32x4 acc[4][4];
#pragma unroll
    for (int r = 0; r < 4; ++r)
#pragma unroll
        for (int c = 0; c < 4; ++c) acc[r][c] = (f32x4){0.f, 0.f, 0.f, 0.f};

    for (int k0 = 0; k0 < 256; k0 += 32) {
        *(uint4*)&As[sr * 40 + sc * 8] =
            *(const uint4*)(A + (size_t)(bm0 + sr) * 256 + k0 + sc * 8);
        {
            const uint4* wp = (const uint4*)(WT + (size_t)(bn0 + tid) * 256 + k0);
#pragma unroll
            for (int c = 0; c < 4; ++c)
                *(uint4*)&Bs[tid * 40 + c * 8] = wp[c];
        }
        __syncthreads();
        bf16x8 a[4], b[4];
#pragma unroll
        for (int r = 0; r < 4; ++r) a[r] = *(const bf16x8*)&As[(r * 16 + fm) * 40 + fk];
#pragma unroll
        for (int c = 0; c < 4; ++c) b[c] = *(const bf16x8*)&Bs[(cw0 + c * 16 + fm) * 40 + fk];
#pragma unroll
        for (int r = 0; r < 4; ++r)
#pragma unroll
            for (int c = 0; c < 4; ++c)
                acc[r][c] = __builtin_amdgcn_mfma_f32_16x16x32_bf16(a[r], b[c], acc[r][c], 0, 0, 0);
        __syncthreads();
    }
#pragma unroll
    for (int c = 0; c < 4; ++c) {
        const int col = bn0 + cw0 + c * 16 + lc;
#pragma unroll
        for (int r = 0; r < 4; ++r)
#pragma unroll
            for (int i = 0; i < 4; ++i) {
                float v = acc[r][c][i];
                v = (v >= 0.f) ? v : 0.01f * v;   // leaky
                C[(size_t)(bm0 + r * 16 + lr + i) * 512 + col] = v;
            }
    }
}

// ---------------------------------------------------------------------------
// Head kernels (f32)
// ---------------------------------------------------------------------------
__global__ void k_pool(const u16* __restrict__ H, u16* __restrict__ Xc)
{
    int c = blockIdx.x, f = threadIdx.x;          // 8192 blocks x 256
    const u16* p = H + (size_t)c * 25 * 256 + f;
    float s = 0.f;
#pragma unroll
    for (int j = 0; j < 25; ++j) s += b2f(p[j * 256]);
    Xc[(size_t)c * 256 + f] = f2b(s / 25.0f);
}

__global__ void k_setpool(const float* __restrict__ T, float* __restrict__ Tp)
{
    int tid = blockIdx.x * 256 + threadIdx.x;     // 4096*64
    int b = tid >> 6, s = tid & 63;
    float acc = 0.f;
#pragma unroll
    for (int c = 0; c < 2; ++c) {
        const float* row = T + ((size_t)(b * 2 + c)) * 512 + s;
        float mx = row[0];
#pragma unroll
        for (int m = 1; m < 8; ++m) mx = fmaxf(mx, row[m * 64]);
        acc += mx;
    }
    Tp[tid] = acc;
}

__global__ void k_fc1(const float* __restrict__ Tp, const float* __restrict__ w,
                      const float* __restrict__ b, float* __restrict__ T1)
{
    int tid = blockIdx.x * 256 + threadIdx.x;     // 4096*32
    int bb = tid >> 5, j = tid & 31;
    float s = b[j];
#pragma unroll
    for (int k = 0; k < 64; ++k) s += Tp[bb * 64 + k] * w[k * 32 + j];
    T1[tid] = s;
}

__global__ void k_bnstats(const float* __restrict__ T1, float* __restrict__ stats)
{
    __shared__ float r1[256], r2[256];
    const int j = blockIdx.x, t = threadIdx.x;    // 32 blocks
    float s = 0.f, ss = 0.f;
    for (int b = t; b < 4096; b += 256) {
        float v = T1[b * 32 + j];
        s += v; ss += v * v;
    }
    r1[t] = s; r2[t] = ss;
    __syncthreads();
    for (int off = 128; off > 0; off >>= 1) {
        if (t < off) { r1[t] += r1[t + off]; r2[t] += r2[t + off]; }
        __syncthreads();
    }
    if (t == 0) {
        float mu  = r1[0] * (1.f / 4096.f);
        float var = r2[0] * (1.f / 4096.f) - mu * mu;
        stats[j]      = mu;
        stats[32 + j] = 1.f / sqrtf(var + 1e-5f);
    }
}

__global__ void k_head(const float* __restrict__ T1, const float* __restrict__ stats,
                       const float* __restrict__ g, const float* __restrict__ bb,
                       const float* __restrict__ w2, const float* __restrict__ b2,
                       float* __restrict__ out)
{
    const int b = blockIdx.x * 256 + threadIdx.x; // 4096
    float l0 = b2[0], l1 = b2[1];
#pragma unroll
    for (int j = 0; j < 32; ++j) {
        float v = (T1[b * 32 + j] - stats[j]) * stats[32 + j] * g[j] + bb[j];
        v = (v >= 0.f) ? v : 0.01f * v;
        l0 += v * w2[j * 2];
        l1 += v * w2[j * 2 + 1];
    }
    float mx  = fmaxf(l0, l1);
    float lse = mx + logf(expf(l0 - mx) + expf(l1 - mx));
    out[b * 2]     = l0 - lse;
    out[b * 2 + 1] = l1 - lse;
}

// ---------------------------------------------------------------------------
extern "C" void kernel_launch(void* const* d_in, const int* in_sizes, int n_in,
                              void* d_out, int out_size, void* d_ws, size_t ws_size,
                              hipStream_t stream)
{
    (void)n_in; (void)out_size; (void)ws_size;
    constexpr int NN = 204800, NCOMP = 8192, NGRAPH = 4096;

    const float* x    = (const float*)d_in[0];
    const float* w0a  = (const float*)d_in[1];
    const float* b0a  = (const float*)d_in[2];
    const float* w0b  = (const float*)d_in[3];
    const float* b0b  = (const float*)d_in[4];
    const float* wra  = (const float*)d_in[5];
    const float* bra  = (const float*)d_in[6];
    const float* wrb  = (const float*)d_in[7];
    const float* brb  = (const float*)d_in[8];
    const float* Wc   = (const float*)d_in[9];
    const float* f1w  = (const float*)d_in[10];
    const float* f1b  = (const float*)d_in[11];
    const float* bng  = (const float*)d_in[12];
    const float* bnb  = (const float*)d_in[13];
    const float* f2w  = (const float*)d_in[14];
    const float* f2bb = (const float*)d_in[15];
    const int* ei   = (const int*)d_in[16];
    const int  E    = in_sizes[16] / 2;           // 409600
    const int* src  = ei;
    const int* dst  = ei + E;

    // ---- workspace layout (~215 MiB) ----
    char* ws = (char*)d_ws;
    u16*    H1  = (u16*)ws;                                  // [N,256] bf16 ping
    u16*    H0  = (u16*)(ws + (size_t)104857600);            // [N,256] bf16 pong (final)
    u16*    wt  = (u16*)(ws + (size_t)209715200);            // transposed bf16 weights, 1 MiB
    u16 *WT0 = wt, *WT1 = wt + 65536, *WT2 = wt + 131072, *WT3 = wt + 196608,
        *WT4 = wt + 262144, *WT5 = wt + 327680, *WT6 = wt + 393216;
    // CSR arrays after weights:
    char* csr = ws + (size_t)210763776;
    int* cnt    = (int*)csr;                                 // [N]
    int* rowptr = (int*)(csr + 819200);                      // [N]
    int* cursor = (int*)(csr + 1638400);                     // [N]
    int* col    = (int*)(csr + 2457600);                     // [E]
    int* bsum   = (int*)(csr + 4096000);                     // [1024]
    int* bscan  = (int*)(csr + 4100096);                     // [1024]
    // head scratch reuses dead H1 region:
    u16*   Xc    = (u16*)ws;                                 // [8192,256] bf16
    float* Tfull = (float*)(ws + (size_t)16777216);          // [8192,512] f32
    float* Tp    = (float*)(ws + (size_t)33554432);          // [4096,64]
    float* T1    = (float*)(ws + (size_t)41943040);          // [4096,32]
    float* stats = (float*)(ws + (size_t)46137344);          // mu[32], rstd[32]

    const dim3 blk(256);
    const int NB = NN / 256;                                  // 800 scan blocks

    // ---- CSR build (once, reused by all 3 layers) ----
    hipMemsetAsync(cnt, 0, NN * 4, stream);
    k_count<<<(E + 255) / 256, blk, 0, stream>>>(dst, cnt, E);
    k_scan1<<<NB, blk, 0, stream>>>(cnt, rowptr, bsum, NN);
    k_scan2<<<1, blk, 0, stream>>>(bsum, bscan, NB);
    k_scan3<<<NB, blk, 0, stream>>>(rowptr, bscan, cursor, NN);
    k_fill<<<(E + 255) / 256, blk, 0, stream>>>(src, dst, cursor, col, E);

    // ---- pre-transpose weights (f32 -> bf16) ----
    k_T<<<128, blk, 0, stream>>>(w0a, WT0, 128, 256);
    k_T<<<256, blk, 0, stream>>>(w0b, WT1, 256, 256);
    k_T<<<256, blk, 0, stream>>>(wra,          WT2, 256, 256);
    k_T<<<256, blk, 0, stream>>>(wra + 65536,  WT3, 256, 256);
    k_T<<<256, blk, 0, stream>>>(wrb,          WT4, 256, 256);
    k_T<<<256, blk, 0, stream>>>(wrb + 65536,  WT5, 256, 256);
    k_T<<<512, blk, 0, stream>>>(Wc, WT6, 256, 512);

    // ---- fused GIN layers (aggregation inside k_gin; H ping-pongs) ----
    // layer 0: src = x (f32, K=128, no relu) -> H0
    k_gin<128, false, true><<<NN / 64, blk, 0, stream>>>(
        x, cnt, rowptr, col, WT0, b0a, WT1, b0b, H0);
    // layer 1: src = H0 (bf16, relu) -> H1
    k_gin<256, true, false><<<NN / 64, blk, 0, stream>>>(
        H0, cnt, rowptr, col, WT2, bra, WT4, brb, H1);
    // layer 2: src = H1 (bf16, relu) -> H0
    k_gin<256, true, false><<<NN / 64, blk, 0, stream>>>(
        H1, cnt, rowptr, col, WT3, bra + 256, WT5, brb + 256, H0);

    // ---- head ----
    k_pool<<<NCOMP, blk, 0, stream>>>(H0, Xc);
    k_lin<<<dim3(NCOMP / 64, 2), blk, 0, stream>>>(Xc, WT6, Tfull);
    k_setpool<<<(NGRAPH * 64) / 256, blk, 0, stream>>>(Tfull, Tp);
    k_fc1<<<(NGRAPH * 32) / 256, blk, 0, stream>>>(Tp, f1w, f1b, T1);
    k_bnstats<<<32, blk, 0, stream>>>(T1, stats);
    k_head<<<NGRAPH / 256, blk, 0, stream>>>(T1, stats, bng, bnb, f2w, f2bb, (float*)d_out);
}

// Round 2
// 804.946 us; speedup vs baseline: 1.1064x; 1.1064x over previous
//
#include <hip/hip_runtime.h>
#include <hip/hip_fp16.h>
#include <math.h>

typedef unsigned short u16;
typedef float f32x4 __attribute__((ext_vector_type(4)));
typedef __bf16 bf16x8 __attribute__((ext_vector_type(8)));

__device__ __forceinline__ float b2f(u16 u) {
    union { unsigned int i; float f; } v; v.i = ((unsigned int)u) << 16; return v.f;
}
__device__ __forceinline__ u16 f2b(float f) {
    union { float f; unsigned int i; } v; v.f = f;
    unsigned int lsb = (v.i >> 16) & 1u;
    return (u16)((v.i + 0x7fffu + lsb) >> 16);   // RNE
}

// ---------------------------------------------------------------------------
// CSR build: counts -> block scan -> global scan -> fill
// ---------------------------------------------------------------------------
__global__ __launch_bounds__(256)
void k_count(const int* __restrict__ dst, int* __restrict__ cnt, int E)
{
    int e = blockIdx.x * 256 + threadIdx.x;
    if (e < E) atomicAdd(&cnt[dst[e]], 1);
}

__global__ __launch_bounds__(256)
void k_scan1(const int* __restrict__ cnt, int* __restrict__ rowptr,
             int* __restrict__ bsum, int N)
{
    __shared__ int s[256];
    int t = threadIdx.x, i = blockIdx.x * 256 + t;
    int v = (i < N) ? cnt[i] : 0;
    s[t] = v;
    __syncthreads();
#pragma unroll
    for (int off = 1; off < 256; off <<= 1) {
        int add = (t >= off) ? s[t - off] : 0;
        __syncthreads();
        s[t] += add;
        __syncthreads();
    }
    if (i < N) rowptr[i] = s[t] - v;
    if (t == 255) bsum[blockIdx.x] = s[255];
}

__global__ __launch_bounds__(256)
void k_scan2(const int* __restrict__ bsum, int* __restrict__ bscan, int nb)
{
    __shared__ int s[256];
    int t = threadIdx.x;
    int g[4], e[4];
    int base = t * 4;
#pragma unroll
    for (int j = 0; j < 4; ++j) g[j] = (base + j < nb) ? bsum[base + j] : 0;
    e[0] = 0; e[1] = g[0]; e[2] = g[0] + g[1]; e[3] = g[0] + g[1] + g[2];
    int tsum = e[3] + g[3];
    s[t] = tsum;
    __syncthreads();
#pragma unroll
    for (int off = 1; off < 256; off <<= 1) {
        int add = (t >= off) ? s[t - off] : 0;
        __syncthreads();
        s[t] += add;
        __syncthreads();
    }
    int texcl = s[t] - tsum;
#pragma unroll
    for (int j = 0; j < 4; ++j)
        if (base + j < nb) bscan[base + j] = texcl + e[j];
}

__global__ __launch_bounds__(256)
void k_scan3(int* __restrict__ rowptr, const int* __restrict__ bscan,
             int* __restrict__ cursor, int N)
{
    int i = blockIdx.x * 256 + threadIdx.x;
    if (i >= N) return;
    int r = rowptr[i] + bscan[i >> 8];
    rowptr[i] = r;
    cursor[i] = r;
}

__global__ __launch_bounds__(256)
void k_fill(const int* __restrict__ src, const int* __restrict__ dst,
            int* __restrict__ cursor, int* __restrict__ col, int E)
{
    int e = blockIdx.x * 256 + threadIdx.x;
    if (e >= E) return;
    int pos = atomicAdd(&cursor[dst[e]], 1);
    col[pos] = src[e];
}

// transpose + f32->bf16 convert: out[n*K+k] = bf16(in[k*N+n])   (weights, tiny)
__global__ void k_T(const float* __restrict__ in, u16* __restrict__ out, int K, int N)
{
    int t = blockIdx.x * 256 + threadIdx.x;
    if (t >= K * N) return;
    int n = t / K, k = t % K;
    out[t] = f2b(in[k * N + n]);
}

// ---------------------------------------------------------------------------
// Fully fused GIN layer, barrier-light version.
//
// Key observation: in this blocking the B (weight) fragment of wave w, col
// group c, K-step kb is exactly the per-lane contiguous 16B slice
//   WT[(w*64 + c*16 + (lane&15))*K + kb*32 + (lane>>4)*8 .. +7]
// i.e. wave-private data with a trivial register layout. So B needs NO LDS
// and NO synchronization: plain global loads (L2-resident weights), which
// the compiler is free to software-pipeline.
//
// A lives in AH (32 KB): written by aggregation, read in phase 1, rewritten
// with the hidden activations, read in phase 2 -> exactly 3 barriers/block.
// LDS 32 KB + <=128 VGPR (launch_bounds 256,4) -> 4 blocks/CU, 16 waves:
// one block's gather latency hides under other blocks' MFMA work.
//
// Aggregation (unchanged math): 4 threads/row, f32 accumulate, one bf16
// round, written in the blocked MFMA-A layout:
//   elem(row,k) -> AH[(k>>5)*2048 + (row>>4)*512 + ((k>>3)&3)*128
//                    + (row&15)*8 + (k&7)]
// ---------------------------------------------------------------------------
template<int K, bool RELU, bool F32SRC>
__global__ __launch_bounds__(256, 4)
void k_gin(const void* __restrict__ hsrc,
           const int* __restrict__ cnt, const int* __restrict__ rowptr,
           const int* __restrict__ col,
           const u16* __restrict__ WaT, const float* __restrict__ ba,
           const u16* __restrict__ WbT, const float* __restrict__ bb,
           u16* __restrict__ Hout)
{
    __shared__ u16 AH[64 * 256];     // 32 KB: Aeff (phase 1) then hidden (phase 2)

    const int tid = threadIdx.x, lane = tid & 63, wave = tid >> 6;
    const int bm0 = blockIdx.x * 64;
    const int lc = lane & 15, lr = (lane >> 4) * 4;
    const int cw0 = wave * 64;
    const int l15 = lane & 15, lq = lane >> 4;

    // ---- fused aggregation into AH ----
    {
        const int r    = tid >> 2;          // 0..63 block row
        const int seg  = tid & 3;           // k segment
        const int node = bm0 + r;
        const int nn = cnt[node], rp = rowptr[node];
        constexpr int KSEG = K / 4;         // 64 (K=256) or 32 (K=128)
        constexpr int NP   = KSEG / 32;     // 2 or 1 passes of 32 k
        u16* const wbase = AH + (r >> 4) * 512 + (r & 15) * 8;
#pragma unroll
        for (int p = 0; p < NP; ++p) {
            const int k0 = seg * KSEG + p * 32;
            float acc[32];
#pragma unroll
            for (int i = 0; i < 32; ++i) acc[i] = 0.f;
            for (int j = -1; j < nn; ++j) {          // j==-1 is own row
                const int sIdx = (j < 0) ? node : col[rp + j];
                if (F32SRC) {
                    const float4* q = (const float4*)((const float*)hsrc + (size_t)sIdx * K + k0);
#pragma unroll
                    for (int cc = 0; cc < 8; ++cc) {
                        float4 v = q[cc];
                        if (RELU) {
                            v.x = fmaxf(v.x, 0.f); v.y = fmaxf(v.y, 0.f);
                            v.z = fmaxf(v.z, 0.f); v.w = fmaxf(v.w, 0.f);
                        }
                        acc[cc * 4 + 0] += v.x; acc[cc * 4 + 1] += v.y;
                        acc[cc * 4 + 2] += v.z; acc[cc * 4 + 3] += v.w;
                    }
                } else {
                    const uint4* q = (const uint4*)((const u16*)hsrc + (size_t)sIdx * K + k0);
#pragma unroll
                    for (int cc = 0; cc < 4; ++cc) {
                        u16 vs[8] __attribute__((aligned(16)));
                        *(uint4*)vs = q[cc];
#pragma unroll
                        for (int i2 = 0; i2 < 8; ++i2) {
                            float x = b2f(vs[i2]);
                            acc[cc * 8 + i2] += RELU ? fmaxf(x, 0.f) : x;
                        }
                    }
                }
            }
            u16* wp = wbase + (k0 >> 5) * 2048;
#pragma unroll
            for (int kc = 0; kc < 4; ++kc) {
                u16 tmp[8] __attribute__((aligned(16)));
#pragma unroll
                for (int jj = 0; jj < 8; ++jj) tmp[jj] = f2b(acc[kc * 8 + jj]);
                *(uint4*)(wp + kc * 128) = *(const uint4*)tmp;
            }
        }
    }
    __syncthreads();                              // AH (Aeff) ready for all waves

    // ---- phase 1: hidden = relu(Aeff @ Wa + ba); B direct-to-reg, no barriers
    constexpr int NK1 = K / 32;
    f32x4 acc1[4][4];
#pragma unroll
    for (int r = 0; r < 4; ++r)
#pragma unroll
        for (int c = 0; c < 4; ++c) acc1[r][c] = (f32x4){0.f, 0.f, 0.f, 0.f};

#pragma unroll
    for (int kb = 0; kb < NK1; ++kb) {
        bf16x8 a[4], b[4];
#pragma unroll
        for (int c = 0; c < 4; ++c)
            b[c] = *(const bf16x8*)(WaT + (size_t)(cw0 + c * 16 + l15) * K + kb * 32 + lq * 8);
#pragma unroll
        for (int r = 0; r < 4; ++r)
            a[r] = *(const bf16x8*)&AH[(kb * 256 + r * 64 + lane) * 8];
        __builtin_amdgcn_s_setprio(1);
#pragma unroll
        for (int r = 0; r < 4; ++r)
#pragma unroll
            for (int c = 0; c < 4; ++c)
                acc1[r][c] = __builtin_amdgcn_mfma_f32_16x16x32_bf16(a[r], b[c], acc1[r][c], 0, 0, 0);
        __builtin_amdgcn_s_setprio(0);
    }
    __syncthreads();                              // all waves done reading Aeff

    // epilogue 1 -> AH (blocked A-layout for phase 2)
    // C/D layout: col = lane&15 (=lc), row = (lane>>4)*4 + i (=lr+i)
#pragma unroll
    for (int c = 0; c < 4; ++c) {
        const int n = cw0 + c * 16 + lc;           // hidden col = phase-2 k
        const float bv = ba[n];
        const int nb = (n >> 5) * 256 + ((n >> 3) & 3) * 16;
#pragma unroll
        for (int r = 0; r < 4; ++r)
#pragma unroll
            for (int i = 0; i < 4; ++i)
                AH[(nb + r * 64 + lr + i) * 8 + (n & 7)] = f2b(fmaxf(acc1[r][c][i] + bv, 0.f));
    }
    __syncthreads();                              // hidden ready

    // ---- phase 2: out = hidden @ Wb + bb; B direct-to-reg, no barriers ----
    f32x4 acc2[4][4];
#pragma unroll
    for (int r = 0; r < 4; ++r)
#pragma unroll
        for (int c = 0; c < 4; ++c) acc2[r][c] = (f32x4){0.f, 0.f, 0.f, 0.f};

#pragma unroll
    for (int kb = 0; kb < 8; ++kb) {
        bf16x8 a[4], b[4];
#pragma unroll
        for (int c = 0; c < 4; ++c)
            b[c] = *(const bf16x8*)(WbT + (size_t)(cw0 + c * 16 + l15) * 256 + kb * 32 + lq * 8);
#pragma unroll
        for (int r = 0; r < 4; ++r)
            a[r] = *(const bf16x8*)&AH[(kb * 256 + r * 64 + lane) * 8];
        __builtin_amdgcn_s_setprio(1);
#pragma unroll
        for (int r = 0; r < 4; ++r)
#pragma unroll
            for (int c = 0; c < 4; ++c)
                acc2[r][c] = __builtin_amdgcn_mfma_f32_16x16x32_bf16(a[r], b[c], acc2[r][c], 0, 0, 0);
        __builtin_amdgcn_s_setprio(0);
    }
#pragma unroll
    for (int c = 0; c < 4; ++c) {
        const int n = cw0 + c * 16 + lc;
        const float bv = bb[n];
#pragma unroll
        for (int r = 0; r < 4; ++r)
#pragma unroll
            for (int i = 0; i < 4; ++i)
                Hout[(size_t)(bm0 + r * 16 + lr + i) * 256 + n] = f2b(acc2[r][c][i] + bv);
    }
}

// ---------------------------------------------------------------------------
// Classifier linear: C[f32] = leaky(A[bf16] @ WT^T), N=512 via 2 n-blocks.
// ---------------------------------------------------------------------------
__global__ __launch_bounds__(256)
void k_lin(const u16* __restrict__ A, const u16* __restrict__ WT,
           float* __restrict__ C)
{
    __shared__ u16 As[64 * 40];
    __shared__ u16 Bs[256 * 40];
    const int tid = threadIdx.x, lane = tid & 63, wave = tid >> 6;
    const int bm0 = blockIdx.x * 64, bn0 = blockIdx.y * 256;
    const int fm = lane & 15, fk = (lane >> 4) * 8;
    const int lc = lane & 15, lr = (lane >> 4) * 4;
    const int cw0 = wave * 64;
    const int sr = tid >> 2, sc = tid & 3;

    f32x4 acc[4][4];
#pragma unroll
    for (int r = 0; r < 4; ++r)
#pragma unroll
        for (int c = 0; c < 4; ++c) acc[r][c] = (f32x4){0.f, 0.f, 0.f, 0.f};

    for (int k0 = 0; k0 < 256; k0 += 32) {
        *(uint4*)&As[sr * 40 + sc * 8] =
            *(const uint4*)(A + (size_t)(bm0 + sr) * 256 + k0 + sc * 8);
        {
            const uint4* wp = (const uint4*)(WT + (size_t)(bn0 + tid) * 256 + k0);
#pragma unroll
            for (int c = 0; c < 4; ++c)
                *(uint4*)&Bs[tid * 40 + c * 8] = wp[c];
        }
        __syncthreads();
        bf16x8 a[4], b[4];
#pragma unroll
        for (int r = 0; r < 4; ++r) a[r] = *(const bf16x8*)&As[(r * 16 + fm) * 40 + fk];
#pragma unroll
        for (int c = 0; c < 4; ++c) b[c] = *(const bf16x8*)&Bs[(cw0 + c * 16 + fm) * 40 + fk];
#pragma unroll
        for (int r = 0; r < 4; ++r)
#pragma unroll
            for (int c = 0; c < 4; ++c)
                acc[r][c] = __builtin_amdgcn_mfma_f32_16x16x32_bf16(a[r], b[c], acc[r][c], 0, 0, 0);
        __syncthreads();
    }
#pragma unroll
    for (int c = 0; c < 4; ++c) {
        const int col = bn0 + cw0 + c * 16 + lc;
#pragma unroll
        for (int r = 0; r < 4; ++r)
#pragma unroll
            for (int i = 0; i < 4; ++i) {
                float v = acc[r][c][i];
                v = (v >= 0.f) ? v : 0.01f * v;   // leaky
                C[(size_t)(bm0 + r * 16 + lr + i) * 512 + col] = v;
            }
    }
}

// ---------------------------------------------------------------------------
// Head kernels (f32)
// ---------------------------------------------------------------------------
__global__ void k_pool(const u16* __restrict__ H, u16* __restrict__ Xc)
{
    int c = blockIdx.x, f = threadIdx.x;          // 8192 blocks x 256
    const u16* p = H + (size_t)c * 25 * 256 + f;
    float s = 0.f;
#pragma unroll
    for (int j = 0; j < 25; ++j) s += b2f(p[j * 256]);
    Xc[(size_t)c * 256 + f] = f2b(s / 25.0f);
}

__global__ void k_setpool(const float* __restrict__ T, float* __restrict__ Tp)
{
    int tid = blockIdx.x * 256 + threadIdx.x;     // 4096*64
    int b = tid >> 6, s = tid & 63;
    float acc = 0.f;
#pragma unroll
    for (int c = 0; c < 2; ++c) {
        const float* row = T + ((size_t)(b * 2 + c)) * 512 + s;
        float mx = row[0];
#pragma unroll
        for (int m = 1; m < 8; ++m) mx = fmaxf(mx, row[m * 64]);
        acc += mx;
    }
    Tp[tid] = acc;
}

__global__ void k_fc1(const float* __restrict__ Tp, const float* __restrict__ w,
                      const float* __restrict__ b, float* __restrict__ T1)
{
    int tid = blockIdx.x * 256 + threadIdx.x;     // 4096*32
    int bb = tid >> 5, j = tid & 31;
    float s = b[j];
#pragma unroll
    for (int k = 0; k < 64; ++k) s += Tp[bb * 64 + k] * w[k * 32 + j];
    T1[tid] = s;
}

__global__ void k_bnstats(const float* __restrict__ T1, float* __restrict__ stats)
{
    __shared__ float r1[256], r2[256];
    const int j = blockIdx.x, t = threadIdx.x;    // 32 blocks
    float s = 0.f, ss = 0.f;
    for (int b = t; b < 4096; b += 256) {
        float v = T1[b * 32 + j];
        s += v; ss += v * v;
    }
    r1[t] = s; r2[t] = ss;
    __syncthreads();
    for (int off = 128; off > 0; off >>= 1) {
        if (t < off) { r1[t] += r1[t + off]; r2[t] += r2[t + off]; }
        __syncthreads();
    }
    if (t == 0) {
        float mu  = r1[0] * (1.f / 4096.f);
        float var = r2[0] * (1.f / 4096.f) - mu * mu;
        stats[j]      = mu;
        stats[32 + j] = 1.f / sqrtf(var + 1e-5f);
    }
}

__global__ void k_head(const float* __restrict__ T1, const float* __restrict__ stats,
                       const float* __restrict__ g, const float* __restrict__ bb,
                       const float* __restrict__ w2, const float* __restrict__ b2,
                       float* __restrict__ out)
{
    const int b = blockIdx.x * 256 + threadIdx.x; // 4096
    float l0 = b2[0], l1 = b2[1];
#pragma unroll
    for (int j = 0; j < 32; ++j) {
        float v = (T1[b * 32 + j] - stats[j]) * stats[32 + j] * g[j] + bb[j];
        v = (v >= 0.f) ? v : 0.01f * v;
        l0 += v * w2[j * 2];
        l1 += v * w2[j * 2 + 1];
    }
    float mx  = fmaxf(l0, l1);
    float lse = mx + logf(expf(l0 - mx) + expf(l1 - mx));
    out[b * 2]     = l0 - lse;
    out[b * 2 + 1] = l1 - lse;
}

// ---------------------------------------------------------------------------
extern "C" void kernel_launch(void* const* d_in, const int* in_sizes, int n_in,
                              void* d_out, int out_size, void* d_ws, size_t ws_size,
                              hipStream_t stream)
{
    (void)n_in; (void)out_size; (void)ws_size;
    constexpr int NN = 204800, NCOMP = 8192, NGRAPH = 4096;

    const float* x    = (const float*)d_in[0];
    const float* w0a  = (const float*)d_in[1];
    const float* b0a  = (const float*)d_in[2];
    const float* w0b  = (const float*)d_in[3];
    const float* b0b  = (const float*)d_in[4];
    const float* wra  = (const float*)d_in[5];
    const float* bra  = (const float*)d_in[6];
    const float* wrb  = (const float*)d_in[7];
    const float* brb  = (const float*)d_in[8];
    const float* Wc   = (const float*)d_in[9];
    const float* f1w  = (const float*)d_in[10];
    const float* f1b  = (const float*)d_in[11];
    const float* bng  = (const float*)d_in[12];
    const float* bnb  = (const float*)d_in[13];
    const float* f2w  = (const float*)d_in[14];
    const float* f2bb = (const float*)d_in[15];
    const int* ei   = (const int*)d_in[16];
    const int  E    = in_sizes[16] / 2;           // 409600
    const int* src  = ei;
    const int* dst  = ei + E;

    // ---- workspace layout (~215 MiB) ----
    char* ws = (char*)d_ws;
    u16*    H1  = (u16*)ws;                                  // [N,256] bf16 ping
    u16*    H0  = (u16*)(ws + (size_t)104857600);            // [N,256] bf16 pong (final)
    u16*    wt  = (u16*)(ws + (size_t)209715200);            // transposed bf16 weights, 1 MiB
    u16 *WT0 = wt, *WT1 = wt + 65536, *WT2 = wt + 131072, *WT3 = wt + 196608,
        *WT4 = wt + 262144, *WT5 = wt + 327680, *WT6 = wt + 393216;
    // CSR arrays after weights:
    char* csr = ws + (size_t)210763776;
    int* cnt    = (int*)csr;                                 // [N]
    int* rowptr = (int*)(csr + 819200);                      // [N]
    int* cursor = (int*)(csr + 1638400);                     // [N]
    int* col    = (int*)(csr + 2457600);                     // [E]
    int* bsum   = (int*)(csr + 4096000);                     // [1024]
    int* bscan  = (int*)(csr + 4100096);                     // [1024]
    // head scratch reuses dead H1 region:
    u16*   Xc    = (u16*)ws;                                 // [8192,256] bf16
    float* Tfull = (float*)(ws + (size_t)16777216);          // [8192,512] f32
    float* Tp    = (float*)(ws + (size_t)33554432);          // [4096,64]
    float* T1    = (float*)(ws + (size_t)41943040);          // [4096,32]
    float* stats = (float*)(ws + (size_t)46137344);          // mu[32], rstd[32]

    const dim3 blk(256);
    const int NB = NN / 256;                                  // 800 scan blocks

    // ---- CSR build (once, reused by all 3 layers) ----
    hipMemsetAsync(cnt, 0, NN * 4, stream);
    k_count<<<(E + 255) / 256, blk, 0, stream>>>(dst, cnt, E);
    k_scan1<<<NB, blk, 0, stream>>>(cnt, rowptr, bsum, NN);
    k_scan2<<<1, blk, 0, stream>>>(bsum, bscan, NB);
    k_scan3<<<NB, blk, 0, stream>>>(rowptr, bscan, cursor, NN);
    k_fill<<<(E + 255) / 256, blk, 0, stream>>>(src, dst, cursor, col, E);

    // ---- pre-transpose weights (f32 -> bf16) ----
    k_T<<<128, blk, 0, stream>>>(w0a, WT0, 128, 256);
    k_T<<<256, blk, 0, stream>>>(w0b, WT1, 256, 256);
    k_T<<<256, blk, 0, stream>>>(wra,          WT2, 256, 256);
    k_T<<<256, blk, 0, stream>>>(wra + 65536,  WT3, 256, 256);
    k_T<<<256, blk, 0, stream>>>(wrb,          WT4, 256, 256);
    k_T<<<256, blk, 0, stream>>>(wrb + 65536,  WT5, 256, 256);
    k_T<<<512, blk, 0, stream>>>(Wc, WT6, 256, 512);

    // ---- fused GIN layers (aggregation inside k_gin; H ping-pongs) ----
    // layer 0: src = x (f32, K=128, no relu) -> H0
    k_gin<128, false, true><<<NN / 64, blk, 0, stream>>>(
        x, cnt, rowptr, col, WT0, b0a, WT1, b0b, H0);
    // layer 1: src = H0 (bf16, relu) -> H1
    k_gin<256, true, false><<<NN / 64, blk, 0, stream>>>(
        H0, cnt, rowptr, col, WT2, bra, WT4, brb, H1);
    // layer 2: src = H1 (bf16, relu) -> H0
    k_gin<256, true, false><<<NN / 64, blk, 0, stream>>>(
        H1, cnt, rowptr, col, WT3, bra + 256, WT5, brb + 256, H0);

    // ---- head ----
    k_pool<<<NCOMP, blk, 0, stream>>>(H0, Xc);
    k_lin<<<dim3(NCOMP / 64, 2), blk, 0, stream>>>(Xc, WT6, Tfull);
    k_setpool<<<(NGRAPH * 64) / 256, blk, 0, stream>>>(Tfull, Tp);
    k_fc1<<<(NGRAPH * 32) / 256, blk, 0, stream>>>(Tp, f1w, f1b, T1);
    k_bnstats<<<32, blk, 0, stream>>>(T1, stats);
    k_head<<<NGRAPH / 256, blk, 0, stream>>>(T1, stats, bng, bnb, f2w, f2bb, (float*)d_out);
}